// Round 13
// baseline (143.090 us; speedup 1.0000x reference)
//
#include <hip/hip_runtime.h>
#include <hip/hip_bf16.h>

typedef short s16x8 __attribute__((ext_vector_type(8)));
typedef unsigned u32x4 __attribute__((ext_vector_type(4)));
typedef unsigned u32x2 __attribute__((ext_vector_type(2)));
typedef float f32x4 __attribute__((ext_vector_type(4)));
typedef float f32x2 __attribute__((ext_vector_type(2)));

// f32 -> bf16 bits, round-to-nearest-even (prep kernel only; not hot)
static __device__ __forceinline__ short f2bf(float f) {
    unsigned u = __builtin_bit_cast(unsigned, f);
    unsigned r = (u + 0x7fffu + ((u >> 16) & 1u)) >> 16;
    return (short)r;
}

// packed f32 pair -> 2x bf16 (RNE) in one dword (v_cvt_pk_bf16_f32)
static __device__ __forceinline__ unsigned pk2bf(float a, float b) {
    __hip_bfloat162 h = __float22bfloat162_rn(make_float2(a, b));
    unsigned r;
    __builtin_memcpy(&r, &h, sizeof(r));
    return r;
}

// Pack Wcat = [W1 | W3] (512 x 128) into bf16 B-fragment order (R1 mapping):
// bws[((kk*8+nt)*64 + l)*8 + j] = Wcat[kk*32 + 8*(l>>4) + j][nt*16 + (l&15)]
__global__ void prep_weights(const float* __restrict__ W1,
                             const float* __restrict__ W3,
                             short* __restrict__ bws) {
    int tid = blockIdx.x * blockDim.x + threadIdx.x;   // 0..65535
    int j  = tid & 7;
    int l  = (tid >> 3) & 63;
    int nt = (tid >> 9) & 7;
    int kk = tid >> 12;
    int k = kk * 32 + ((l >> 4) << 3) + j;
    int n = nt * 16 + (l & 15);
    float v = (n < 64) ? W1[k * 64 + n] : W3[k * 64 + (n - 64)];
    bws[tid] = f2bf(v);
}

// R13: fully LINEAR global A-reads (one 1KB-contiguous instruction per
// row-half — the granularity that hits 6.6 TB/s in fill/copy µbenches),
// redistributed to MFMA fragment order via XOR-swizzled LDS staging.
// A-half 64 KiB + B-half 64 KiB = 128 KiB LDS, 8 waves, grid 2048.
// Arithmetic / B path / epilogue identical to verified R10.
__global__ __launch_bounds__(512, 2)
void mf2_main(const float* __restrict__ probs, const float* __restrict__ x,
              const short* __restrict__ bws,
              const float* __restrict__ b1, const float* __restrict__ W2,
              const float* __restrict__ b2, const float* __restrict__ b3,
              const float* __restrict__ W4, const float* __restrict__ b4,
              float* __restrict__ out)
{
    __shared__ short bsh[256 * 128];   // 64 KiB: B K-half (8 kk-steps)
    __shared__ short ash[128 * 256];   // 64 KiB: A K-half (128 rows x 256 k, bf16)

    const int tid  = threadIdx.x;      // 0..511 (8 waves)
    const int lane = tid & 63;
    const int w    = tid >> 6;         // 0..7
    const int g    = lane >> 4;        // 0..3  (MFMA k-chunk group)
    const int m    = lane & 15;        // 0..15 (A-row / C-col)
    const long waveRow = (long)blockIdx.x * 128 + w * 16;   // 16 rows per wave

    // Linear A reads: instruction `it` covers row (waveRow+it), k-half h,
    // 64 lanes x 16B = 1KB CONTIGUOUS. Lane's 4 floats = k (h*256 + lane*4 ..+4)
    // -> fragment (kk=lane>>3, g2=(lane>>1)&3), j-half = lane&1 of row `it`.
    const float* xw = x + waveRow * 512 + lane * 4;

    // A-LDS layout (per wave 8 KiB): addr = w*8192 + kk*1024 + (g2*16+row)*16 + jh*8,
    // XOR-swizzled with kk to break the 32-way write conflict (reads stay
    // canonical conflict-free stride-16 ds_read_b128).
    const int kkL = lane >> 3, g2 = (lane >> 1) & 3, jh = lane & 1;
    char* ab = (char*)ash;

    f32x4 ra[16];

    // ---- A burst, half 0: 16 x 1KB linear ----
    #pragma unroll
    for (int it = 0; it < 16; ++it)
        ra[it] = *(const f32x4*)(xw + it * 512);

    // ---- stage B half 0 ----
    const f32x4* bsrc = (const f32x4*)bws;
    f32x4* bdst = (f32x4*)bsh;
    #pragma unroll
    for (int it = 0; it < 8; ++it)
        bdst[it * 512 + tid] = bsrc[it * 512 + tid];

    // ---- cvt + swizzled ds_write A half 0 ----
    #pragma unroll
    for (int it = 0; it < 16; ++it) {
        u32x2 v;
        v[0] = pk2bf(ra[it][0], ra[it][1]);
        v[1] = pk2bf(ra[it][2], ra[it][3]);
        int addr = w * 8192 + kkL * 1024 + (g2 * 16 + it) * 16 + jh * 8;
        addr ^= ((addr >> 10) & 7) << 4;
        *(u32x2*)(ab + addr) = v;
    }
    __syncthreads();

    const s16x8* bls = (const s16x8*)bsh + lane;

    f32x4 acc[8];
    #pragma unroll
    for (int nt = 0; nt < 8; ++nt)
        acc[nt] = (f32x4){0.f, 0.f, 0.f, 0.f};

    // ---- A burst, half 1 (in flight under the 64 MFMAs below) ----
    #pragma unroll
    for (int it = 0; it < 16; ++it)
        ra[it] = *(const f32x4*)(xw + it * 512 + 256);

    // ---- MFMA half 0 ----
    #pragma unroll
    for (int kk = 0; kk < 8; ++kk) {
        int aaddr = w * 8192 + kk * 1024 + lane * 16;
        aaddr ^= ((aaddr >> 10) & 7) << 4;
        s16x8 a = *(const s16x8*)(ab + aaddr);
        #pragma unroll
        for (int nt = 0; nt < 8; ++nt) {
            s16x8 b = bls[kk * 512 + nt * 64];
            acc[nt] = __builtin_amdgcn_mfma_f32_16x16x32_bf16(a, b, acc[nt], 0, 0, 0);
        }
    }
    __syncthreads();   // all reads of half-0 LDS done

    // ---- stage B half 1 + cvt/write A half 1 ----
    #pragma unroll
    for (int it = 0; it < 8; ++it)
        bdst[it * 512 + tid] = bsrc[4096 + it * 512 + tid];
    #pragma unroll
    for (int it = 0; it < 16; ++it) {
        u32x2 v;
        v[0] = pk2bf(ra[it][0], ra[it][1]);
        v[1] = pk2bf(ra[it][2], ra[it][3]);
        int addr = w * 8192 + kkL * 1024 + (g2 * 16 + it) * 16 + jh * 8;
        addr ^= ((addr >> 10) & 7) << 4;
        *(u32x2*)(ab + addr) = v;
    }
    __syncthreads();

    // ---- MFMA half 1 ----
    #pragma unroll
    for (int kk = 0; kk < 8; ++kk) {
        int aaddr = w * 8192 + kk * 1024 + lane * 16;
        aaddr ^= ((aaddr >> 10) & 7) << 4;
        s16x8 a = *(const s16x8*)(ab + aaddr);
        #pragma unroll
        for (int nt = 0; nt < 8; ++nt) {
            s16x8 b = bls[kk * 512 + nt * 64];
            acc[nt] = __builtin_amdgcn_mfma_f32_16x16x32_bf16(a, b, acc[nt], 0, 0, 0);
        }
    }

    // ---- epilogue (identical to R10) ----
    float w2r[4][4];
    float w4r[4][2];
    float biasr[8];
    #pragma unroll
    for (int nt = 0; nt < 4; ++nt) {
        const int col = m + 16 * nt;
        f32x4 w2v = *(const f32x4*)(W2 + col * 4);
        #pragma unroll
        for (int c = 0; c < 4; ++c) w2r[nt][c] = w2v[c];
        f32x2 w4v = *(const f32x2*)(W4 + col * 2);
        w4r[nt][0] = w4v[0]; w4r[nt][1] = w4v[1];
    }
    #pragma unroll
    for (int nt = 0; nt < 8; ++nt) {
        const int col = m + 16 * nt;
        biasr[nt] = (col < 64) ? b1[col] : b3[col - 64];
    }
    float b2v[4], b4v[2];
    #pragma unroll
    for (int c = 0; c < 4; ++c) b2v[c] = b2[c];
    #pragma unroll
    for (int c = 0; c < 2; ++c) b4v[c] = b4[c];

    // bias+relu, layer-2 partials, 16-lane butterfly reduce.
    // C layout: lane holds row 4*g + r, col m + 16*nt (reg r).
    float own[6] = {0.f, 0.f, 0.f, 0.f, 0.f, 0.f};
    #pragma unroll
    for (int r = 0; r < 4; ++r) {
        float v[6] = {0.f, 0.f, 0.f, 0.f, 0.f, 0.f};
        #pragma unroll
        for (int nt = 0; nt < 4; ++nt) {
            float h = fmaxf(acc[nt][r] + biasr[nt], 0.f);
            v[0] += h * w2r[nt][0];
            v[1] += h * w2r[nt][1];
            v[2] += h * w2r[nt][2];
            v[3] += h * w2r[nt][3];
        }
        #pragma unroll
        for (int j = 0; j < 4; ++j) {
            float h = fmaxf(acc[4 + j][r] + biasr[4 + j], 0.f);
            v[4] += h * w4r[j][0];
            v[5] += h * w4r[j][1];
        }
        #pragma unroll
        for (int msk = 1; msk <= 8; msk <<= 1) {
            #pragma unroll
            for (int c = 0; c < 6; ++c) v[c] += __shfl_xor(v[c], msk, 64);
        }
        if (m == r) {
            #pragma unroll
            for (int c = 0; c < 6; ++c) own[c] = v[c];
        }
    }

    // lanes m<4 finish one row each: sigmoid head + 2-class softmax
    if (m < 4) {
        const long row = waveRow + g * 4 + m;
        f32x4 pr = *(const f32x4*)(probs + row * 4);   // p00 p01 p10 p11
        float mu1[2], mu2[2], icv[2];
        #pragma unroll
        for (int c = 0; c < 2; ++c) {
            mu1[c] = 1.0f / (1.0f + __expf(-(own[c]     + b2v[c])));
            mu2[c] = 1.0f / (1.0f + __expf(-(own[2 + c] + b2v[2 + c])));
            icv[c] = 1.0f / (1.0f + __expf(-(own[4 + c] + b4v[c])));
        }
        float res[2];
        #pragma unroll
        for (int c = 0; c < 2; ++c) {
            float p0 = pr[c], p1 = pr[2 + c];
            float m12 = fminf(fmaxf(mu1[c], mu2[c]) + icv[c], 1.0f);
            res[c] = (p0 <= p1) ? (p0 * mu1[c] + (p1 - p0) * m12)
                                : (p1 * mu2[c] + (p0 - p1) * m12);
        }
        float d01 = res[0] - res[1];
        f32x2 o;
        o[0] = 1.0f / (1.0f + __expf(-d01));
        o[1] = 1.0f / (1.0f + __expf(d01));
        *(f32x2*)(out + row * 2) = o;
    }
}

extern "C" void kernel_launch(void* const* d_in, const int* in_sizes, int n_in,
                              void* d_out, int out_size, void* d_ws, size_t ws_size,
                              hipStream_t stream)
{
    const float* probs = (const float*)d_in[0];
    const float* x     = (const float*)d_in[1];
    const float* W1    = (const float*)d_in[2];
    const float* b1    = (const float*)d_in[3];
    const float* W2    = (const float*)d_in[4];
    const float* b2    = (const float*)d_in[5];
    const float* W3    = (const float*)d_in[6];
    const float* b3    = (const float*)d_in[7];
    const float* W4    = (const float*)d_in[8];
    const float* b4    = (const float*)d_in[9];
    float* out = (float*)d_out;
    short* bws = (short*)d_ws;   // 512*128 bf16 = 128 KiB

    hipLaunchKernelGGL(prep_weights, dim3(256), dim3(256), 0, stream, W1, W3, bws);
    hipLaunchKernelGGL(mf2_main, dim3(2048), dim3(512), 0, stream,
                       probs, x, bws, b1, W2, b2, b3, W4, b4, out);
}

// Round 14
// 121.367 us; speedup vs baseline: 1.1790x; 1.1790x over previous
//
#include <hip/hip_runtime.h>
#include <hip/hip_bf16.h>

typedef short s16x8 __attribute__((ext_vector_type(8)));
typedef unsigned u32x4 __attribute__((ext_vector_type(4)));
typedef float f32x4 __attribute__((ext_vector_type(4)));
typedef float f32x2 __attribute__((ext_vector_type(2)));

// f32 -> bf16 bits, round-to-nearest-even (prep kernel only; not hot)
static __device__ __forceinline__ short f2bf(float f) {
    unsigned u = __builtin_bit_cast(unsigned, f);
    unsigned r = (u + 0x7fffu + ((u >> 16) & 1u)) >> 16;
    return (short)r;
}

// packed f32 pair -> 2x bf16 (RNE) in one dword (v_cvt_pk_bf16_f32)
static __device__ __forceinline__ unsigned pk2bf(float a, float b) {
    __hip_bfloat162 h = __float22bfloat162_rn(make_float2(a, b));
    unsigned r;
    __builtin_memcpy(&r, &h, sizeof(r));
    return r;
}

// Pack Wcat = [W1 | W3] (512 x 128) into bf16 B-fragment order (R1 mapping):
// bws[((kk*8+nt)*64 + l)*8 + j] = Wcat[kk*32 + 8*(l>>4) + j][nt*16 + (l&15)]
__global__ void prep_weights(const float* __restrict__ W1,
                             const float* __restrict__ W3,
                             short* __restrict__ bws) {
    int tid = blockIdx.x * blockDim.x + threadIdx.x;   // 0..65535
    int j  = tid & 7;
    int l  = (tid >> 3) & 63;
    int nt = (tid >> 9) & 7;
    int kk = tid >> 12;
    int k = kk * 32 + ((l >> 4) << 3) + j;
    int n = nt * 16 + (l & 15);
    float v = (n < 64) ? W1[k * 64 + n] : W3[k * 64 + (n - 64)];
    bws[tid] = f2bf(v);
}

// R14 = R5 frame + R10 burst schedule:
// 1024 threads (16 waves, 4/SIMD), FULL 128 KiB B-tile staged ONCE per block
// (no mid-block restage, single barrier), 16 rows/wave, grid 1024.
// A-loads in 4-kk bursts (512 B per row-visit) with next-burst overlap —
// the one verified lever (R10, +6%).
__global__ __launch_bounds__(1024, 4)
void mf2_main(const float* __restrict__ probs, const float* __restrict__ x,
              const short* __restrict__ bws,
              const float* __restrict__ b1, const float* __restrict__ W2,
              const float* __restrict__ b2, const float* __restrict__ b3,
              const float* __restrict__ W4, const float* __restrict__ b4,
              float* __restrict__ out)
{
    __shared__ short bsh[512 * 128];   // 128 KiB: full packed [W1|W3] tile

    const int tid  = threadIdx.x;      // 0..1023 (16 waves)
    const int lane = tid & 63;
    const int g    = lane >> 4;        // 0..3  (k-chunk group)
    const int m    = lane & 15;        // 0..15 (A-row / C-col)
    const long rowBase = (long)blockIdx.x * 256 + (tid >> 6) * 16;   // 16 rows/wave

    // A loads: lane reads 8 contiguous f32 of row (rowBase + m), k-chunk 8*g
    const float* xp = x + (rowBase + m) * 512 + g * 8;

    f32x4 ra[4][2];   // raw burst buffer (one 4-kk burst)
    s16x8 af[4];      // converted bf16 fragments for the burst being consumed

    // ---- burst 0 (kk 0..3): 8 back-to-back loads BEFORE staging ----
    #pragma unroll
    for (int p = 0; p < 4; ++p) {
        const float* pp = xp + p * 32;
        ra[p][0] = *(const f32x4*)pp;
        ra[p][1] = *(const f32x4*)(pp + 4);
    }

    // ---- stage FULL packed B into LDS once (coalesced, conflict-free) ----
    {
        const f32x4* src = (const f32x4*)bws;   // 8192 x 16B
        f32x4* dst = (f32x4*)bsh;
        #pragma unroll
        for (int it = 0; it < 8; ++it) {
            const int idx = it * 1024 + tid;
            dst[idx] = src[idx];
        }
    }
    __syncthreads();

    const s16x8* bls = (const s16x8*)bsh + lane;

    f32x4 acc[8];
    #pragma unroll
    for (int nt = 0; nt < 8; ++nt)
        acc[nt] = (f32x4){0.f, 0.f, 0.f, 0.f};

    #pragma unroll
    for (int burst = 0; burst < 4; ++burst) {
        // convert current burst raw -> bf16 fragments (frees ra)
        #pragma unroll
        for (int s = 0; s < 4; ++s) {
            u32x4 pa;
            pa[0] = pk2bf(ra[s][0][0], ra[s][0][1]);
            pa[1] = pk2bf(ra[s][0][2], ra[s][0][3]);
            pa[2] = pk2bf(ra[s][1][0], ra[s][1][1]);
            pa[3] = pk2bf(ra[s][1][2], ra[s][1][3]);
            af[s] = __builtin_bit_cast(s16x8, pa);
        }

        // issue next burst (8 back-to-back loads, 512 B per row-visit) —
        // in flight under the 32-MFMA block below
        if (burst < 3) {
            #pragma unroll
            for (int p = 0; p < 4; ++p) {
                const float* pp = xp + (burst + 1) * 128 + p * 32;
                ra[p][0] = *(const f32x4*)pp;
                ra[p][1] = *(const f32x4*)(pp + 4);
            }
        }

        // 4 MFMA sub-steps for this burst; B fragments from LDS (full K)
        #pragma unroll
        for (int s = 0; s < 4; ++s) {
            const int kk = burst * 4 + s;
            #pragma unroll
            for (int nt = 0; nt < 8; ++nt) {
                s16x8 b = bls[kk * 512 + nt * 64];
                acc[nt] = __builtin_amdgcn_mfma_f32_16x16x32_bf16(af[s], b, acc[nt], 0, 0, 0);
            }
        }
    }

    // ---- epilogue (weight/bias loads deferred past the loop) ----
    float w2r[4][4];
    float w4r[4][2];
    float biasr[8];
    #pragma unroll
    for (int nt = 0; nt < 4; ++nt) {
        const int col = m + 16 * nt;
        f32x4 w2v = *(const f32x4*)(W2 + col * 4);
        #pragma unroll
        for (int c = 0; c < 4; ++c) w2r[nt][c] = w2v[c];
        f32x2 w4v = *(const f32x2*)(W4 + col * 2);
        w4r[nt][0] = w4v[0]; w4r[nt][1] = w4v[1];
    }
    #pragma unroll
    for (int nt = 0; nt < 8; ++nt) {
        const int col = m + 16 * nt;
        biasr[nt] = (col < 64) ? b1[col] : b3[col - 64];
    }
    float b2v[4], b4v[2];
    #pragma unroll
    for (int c = 0; c < 4; ++c) b2v[c] = b2[c];
    #pragma unroll
    for (int c = 0; c < 2; ++c) b4v[c] = b4[c];

    // bias+relu, layer-2 partials, 16-lane butterfly reduce.
    // C layout: lane holds row 4*g + r, col m + 16*nt (reg r).
    float own[6] = {0.f, 0.f, 0.f, 0.f, 0.f, 0.f};
    #pragma unroll
    for (int r = 0; r < 4; ++r) {
        float v[6] = {0.f, 0.f, 0.f, 0.f, 0.f, 0.f};
        #pragma unroll
        for (int nt = 0; nt < 4; ++nt) {
            float h = fmaxf(acc[nt][r] + biasr[nt], 0.f);
            v[0] += h * w2r[nt][0];
            v[1] += h * w2r[nt][1];
            v[2] += h * w2r[nt][2];
            v[3] += h * w2r[nt][3];
        }
        #pragma unroll
        for (int j = 0; j < 4; ++j) {
            float h = fmaxf(acc[4 + j][r] + biasr[4 + j], 0.f);
            v[4] += h * w4r[j][0];
            v[5] += h * w4r[j][1];
        }
        #pragma unroll
        for (int msk = 1; msk <= 8; msk <<= 1) {
            #pragma unroll
            for (int c = 0; c < 6; ++c) v[c] += __shfl_xor(v[c], msk, 64);
        }
        if (m == r) {
            #pragma unroll
            for (int c = 0; c < 6; ++c) own[c] = v[c];
        }
    }

    // lanes m<4 finish one row each: sigmoid head + 2-class softmax
    if (m < 4) {
        const long row = rowBase + g * 4 + m;
        f32x4 pr = *(const f32x4*)(probs + row * 4);   // p00 p01 p10 p11
        float mu1[2], mu2[2], icv[2];
        #pragma unroll
        for (int c = 0; c < 2; ++c) {
            mu1[c] = 1.0f / (1.0f + __expf(-(own[c]     + b2v[c])));
            mu2[c] = 1.0f / (1.0f + __expf(-(own[2 + c] + b2v[2 + c])));
            icv[c] = 1.0f / (1.0f + __expf(-(own[4 + c] + b4v[c])));
        }
        float res[2];
        #pragma unroll
        for (int c = 0; c < 2; ++c) {
            float p0 = pr[c], p1 = pr[2 + c];
            float m12 = fminf(fmaxf(mu1[c], mu2[c]) + icv[c], 1.0f);
            res[c] = (p0 <= p1) ? (p0 * mu1[c] + (p1 - p0) * m12)
                                : (p1 * mu2[c] + (p0 - p1) * m12);
        }
        float d01 = res[0] - res[1];
        f32x2 o;
        o[0] = 1.0f / (1.0f + __expf(-d01));
        o[1] = 1.0f / (1.0f + __expf(d01));
        *(f32x2*)(out + row * 2) = o;
    }
}

extern "C" void kernel_launch(void* const* d_in, const int* in_sizes, int n_in,
                              void* d_out, int out_size, void* d_ws, size_t ws_size,
                              hipStream_t stream)
{
    const float* probs = (const float*)d_in[0];
    const float* x     = (const float*)d_in[1];
    const float* W1    = (const float*)d_in[2];
    const float* b1    = (const float*)d_in[3];
    const float* W2    = (const float*)d_in[4];
    const float* b2    = (const float*)d_in[5];
    const float* W3    = (const float*)d_in[6];
    const float* b3    = (const float*)d_in[7];
    const float* W4    = (const float*)d_in[8];
    const float* b4    = (const float*)d_in[9];
    float* out = (float*)d_out;
    short* bws = (short*)d_ws;   // 512*128 bf16 = 128 KiB

    hipLaunchKernelGGL(prep_weights, dim3(256), dim3(256), 0, stream, W1, W3, bws);
    hipLaunchKernelGGL(mf2_main, dim3(1024), dim3(1024), 0, stream,
                       probs, x, bws, b1, W2, b2, b3, W4, b4, out);
}

// Round 15
// 119.520 us; speedup vs baseline: 1.1972x; 1.0155x over previous
//
#include <hip/hip_runtime.h>
#include <hip/hip_bf16.h>

typedef short s16x8 __attribute__((ext_vector_type(8)));
typedef unsigned u32x4 __attribute__((ext_vector_type(4)));
typedef float f32x4 __attribute__((ext_vector_type(4)));
typedef float f32x2 __attribute__((ext_vector_type(2)));

// f32 -> bf16 bits, round-to-nearest-even (prep kernel only; not hot)
static __device__ __forceinline__ short f2bf(float f) {
    unsigned u = __builtin_bit_cast(unsigned, f);
    unsigned r = (u + 0x7fffu + ((u >> 16) & 1u)) >> 16;
    return (short)r;
}

// packed f32 pair -> 2x bf16 (RNE) in one dword (v_cvt_pk_bf16_f32)
static __device__ __forceinline__ unsigned pk2bf(float a, float b) {
    __hip_bfloat162 h = __float22bfloat162_rn(make_float2(a, b));
    unsigned r;
    __builtin_memcpy(&r, &h, sizeof(r));
    return r;
}

// Pack Wcat = [W1 | W3] (512 x 128) into bf16 B-fragment order (R1 mapping):
// bws[((kk*8+nt)*64 + l)*8 + j] = Wcat[kk*32 + 8*(l>>4) + j][nt*16 + (l&15)]
__global__ void prep_weights(const float* __restrict__ W1,
                             const float* __restrict__ W3,
                             short* __restrict__ bws) {
    int tid = blockIdx.x * blockDim.x + threadIdx.x;   // 0..65535
    int j  = tid & 7;
    int l  = (tid >> 3) & 63;
    int nt = (tid >> 9) & 7;
    int kk = tid >> 12;
    int k = kk * 32 + ((l >> 4) << 3) + j;
    int n = nt * 16 + (l & 15);
    float v = (n < 64) ? W1[k * 64 + n] : W3[k * 64 + (n - 64)];
    bws[tid] = f2bf(v);
}

// VERIFIED OPTIMUM (R10, 119.4 us): 8 waves, 16 rows/wave, 64 KiB half-K
// B-tile (re-staged mid-block), 2 blocks/CU, grid 2048. A-loads in 4-kk
// BURSTS (8 back-to-back dwordx4 = 512 B per row-visit) with the next
// burst issued under the current 32-MFMA block. Burst clumping was the
// single confirmed lever (+6%); depth/permute/NT/co-residency/linear-LDS
// all measured neutral or negative.
__global__ __launch_bounds__(512, 4)
void mf2_main(const float* __restrict__ probs, const float* __restrict__ x,
              const short* __restrict__ bws,
              const float* __restrict__ b1, const float* __restrict__ W2,
              const float* __restrict__ b2, const float* __restrict__ b3,
              const float* __restrict__ W4, const float* __restrict__ b4,
              float* __restrict__ out)
{
    __shared__ short bsh[256 * 128];   // 64 KiB: 8 kk-steps of packed [W1|W3]

    const int tid  = threadIdx.x;      // 0..511 (8 waves)
    const int lane = tid & 63;
    const int g    = lane >> 4;        // 0..3  (k-chunk group)
    const int m    = lane & 15;        // 0..15 (A-row / C-col)
    const long rowBase = (long)blockIdx.x * 128 + (tid >> 6) * 16;   // 16 rows/wave

    // A loads: lane reads 8 contiguous f32 of row (rowBase + m), k-chunk 8*g
    const float* xp = x + (rowBase + m) * 512 + g * 8;

    f32x4 ra[4][2];   // raw burst buffer (one 4-kk burst)
    s16x8 af[4];      // converted bf16 fragments for the burst being consumed

    // ---- burst 0 (kk 0..3): 8 back-to-back loads BEFORE staging ----
    #pragma unroll
    for (int p = 0; p < 4; ++p) {
        const float* pp = xp + p * 32;
        ra[p][0] = *(const f32x4*)pp;
        ra[p][1] = *(const f32x4*)(pp + 4);
    }

    // ---- stage K-half 0 (64 KiB) ----
    {
        const f32x4* src = (const f32x4*)bws;
        f32x4* dst = (f32x4*)bsh;
        #pragma unroll
        for (int it = 0; it < 8; ++it) {
            const int idx = it * 512 + tid;
            dst[idx] = src[idx];
        }
    }
    __syncthreads();

    const s16x8* bls = (const s16x8*)bsh + lane;

    f32x4 acc[8];
    #pragma unroll
    for (int nt = 0; nt < 8; ++nt)
        acc[nt] = (f32x4){0.f, 0.f, 0.f, 0.f};

    #pragma unroll
    for (int burst = 0; burst < 4; ++burst) {
        // convert current burst raw -> bf16 fragments (frees ra)
        #pragma unroll
        for (int s = 0; s < 4; ++s) {
            u32x4 pa;
            pa[0] = pk2bf(ra[s][0][0], ra[s][0][1]);
            pa[1] = pk2bf(ra[s][0][2], ra[s][0][3]);
            pa[2] = pk2bf(ra[s][1][0], ra[s][1][1]);
            pa[3] = pk2bf(ra[s][1][2], ra[s][1][3]);
            af[s] = __builtin_bit_cast(s16x8, pa);
        }

        // issue next burst (8 back-to-back loads, 512 B per row) — in flight
        // under the 32-MFMA block below
        if (burst < 3) {
            #pragma unroll
            for (int p = 0; p < 4; ++p) {
                const float* pp = xp + (burst + 1) * 128 + p * 32;
                ra[p][0] = *(const f32x4*)pp;
                ra[p][1] = *(const f32x4*)(pp + 4);
            }
        }

        // mid-block: re-stage B K-half 1 (burst-2 loads remain in flight)
        if (burst == 2) {
            __syncthreads();
            const f32x4* src = (const f32x4*)bws;
            f32x4* dst = (f32x4*)bsh;
            #pragma unroll
            for (int it = 0; it < 8; ++it) {
                const int idx = it * 512 + tid;
                dst[idx] = src[4096 + idx];
            }
            __syncthreads();
        }

        // 4 MFMA sub-steps for this burst; B fragments from LDS
        #pragma unroll
        for (int s = 0; s < 4; ++s) {
            const int k8 = (burst & 1) * 4 + s;   // kk within current B half
            #pragma unroll
            for (int nt = 0; nt < 8; ++nt) {
                s16x8 b = bls[k8 * 512 + nt * 64];
                acc[nt] = __builtin_amdgcn_mfma_f32_16x16x32_bf16(af[s], b, acc[nt], 0, 0, 0);
            }
        }
    }

    // ---- epilogue (weight/bias loads deferred past the loop) ----
    float w2r[4][4];
    float w4r[4][2];
    float biasr[8];
    #pragma unroll
    for (int nt = 0; nt < 4; ++nt) {
        const int col = m + 16 * nt;
        f32x4 w2v = *(const f32x4*)(W2 + col * 4);
        #pragma unroll
        for (int c = 0; c < 4; ++c) w2r[nt][c] = w2v[c];
        f32x2 w4v = *(const f32x2*)(W4 + col * 2);
        w4r[nt][0] = w4v[0]; w4r[nt][1] = w4v[1];
    }
    #pragma unroll
    for (int nt = 0; nt < 8; ++nt) {
        const int col = m + 16 * nt;
        biasr[nt] = (col < 64) ? b1[col] : b3[col - 64];
    }
    float b2v[4], b4v[2];
    #pragma unroll
    for (int c = 0; c < 4; ++c) b2v[c] = b2[c];
    #pragma unroll
    for (int c = 0; c < 2; ++c) b4v[c] = b4[c];

    // bias+relu, layer-2 partials, 16-lane butterfly reduce.
    // C layout: lane holds row 4*g + r, col m + 16*nt (reg r).
    float own[6] = {0.f, 0.f, 0.f, 0.f, 0.f, 0.f};
    #pragma unroll
    for (int r = 0; r < 4; ++r) {
        float v[6] = {0.f, 0.f, 0.f, 0.f, 0.f, 0.f};
        #pragma unroll
        for (int nt = 0; nt < 4; ++nt) {
            float h = fmaxf(acc[nt][r] + biasr[nt], 0.f);
            v[0] += h * w2r[nt][0];
            v[1] += h * w2r[nt][1];
            v[2] += h * w2r[nt][2];
            v[3] += h * w2r[nt][3];
        }
        #pragma unroll
        for (int j = 0; j < 4; ++j) {
            float h = fmaxf(acc[4 + j][r] + biasr[4 + j], 0.f);
            v[4] += h * w4r[j][0];
            v[5] += h * w4r[j][1];
        }
        #pragma unroll
        for (int msk = 1; msk <= 8; msk <<= 1) {
            #pragma unroll
            for (int c = 0; c < 6; ++c) v[c] += __shfl_xor(v[c], msk, 64);
        }
        if (m == r) {
            #pragma unroll
            for (int c = 0; c < 6; ++c) own[c] = v[c];
        }
    }

    // lanes m<4 finish one row each: sigmoid head + 2-class softmax
    if (m < 4) {
        const long row = rowBase + g * 4 + m;
        f32x4 pr = *(const f32x4*)(probs + row * 4);   // p00 p01 p10 p11
        float mu1[2], mu2[2], icv[2];
        #pragma unroll
        for (int c = 0; c < 2; ++c) {
            mu1[c] = 1.0f / (1.0f + __expf(-(own[c]     + b2v[c])));
            mu2[c] = 1.0f / (1.0f + __expf(-(own[2 + c] + b2v[2 + c])));
            icv[c] = 1.0f / (1.0f + __expf(-(own[4 + c] + b4v[c])));
        }
        float res[2];
        #pragma unroll
        for (int c = 0; c < 2; ++c) {
            float p0 = pr[c], p1 = pr[2 + c];
            float m12 = fminf(fmaxf(mu1[c], mu2[c]) + icv[c], 1.0f);
            res[c] = (p0 <= p1) ? (p0 * mu1[c] + (p1 - p0) * m12)
                                : (p1 * mu2[c] + (p0 - p1) * m12);
        }
        float d01 = res[0] - res[1];
        f32x2 o;
        o[0] = 1.0f / (1.0f + __expf(-d01));
        o[1] = 1.0f / (1.0f + __expf(d01));
        *(f32x2*)(out + row * 2) = o;
    }
}

extern "C" void kernel_launch(void* const* d_in, const int* in_sizes, int n_in,
                              void* d_out, int out_size, void* d_ws, size_t ws_size,
                              hipStream_t stream)
{
    const float* probs = (const float*)d_in[0];
    const float* x     = (const float*)d_in[1];
    const float* W1    = (const float*)d_in[2];
    const float* b1    = (const float*)d_in[3];
    const float* W2    = (const float*)d_in[4];
    const float* b2    = (const float*)d_in[5];
    const float* W3    = (const float*)d_in[6];
    const float* b3    = (const float*)d_in[7];
    const float* W4    = (const float*)d_in[8];
    const float* b4    = (const float*)d_in[9];
    float* out = (float*)d_out;
    short* bws = (short*)d_ws;   // 512*128 bf16 = 128 KiB

    hipLaunchKernelGGL(prep_weights, dim3(256), dim3(256), 0, stream, W1, W3, bws);
    hipLaunchKernelGGL(mf2_main, dim3(2048), dim3(512), 0, stream,
                       probs, x, bws, b1, W2, b2, b3, W4, b4, out);
}

// Round 16
// 119.337 us; speedup vs baseline: 1.1990x; 1.0015x over previous
//
#include <hip/hip_runtime.h>
#include <hip/hip_bf16.h>

typedef short s16x8 __attribute__((ext_vector_type(8)));
typedef unsigned u32x4 __attribute__((ext_vector_type(4)));
typedef float f32x4 __attribute__((ext_vector_type(4)));
typedef float f32x2 __attribute__((ext_vector_type(2)));

// f32 -> bf16 bits, round-to-nearest-even (prep kernel only; not hot)
static __device__ __forceinline__ short f2bf(float f) {
    unsigned u = __builtin_bit_cast(unsigned, f);
    unsigned r = (u + 0x7fffu + ((u >> 16) & 1u)) >> 16;
    return (short)r;
}

// packed f32 pair -> 2x bf16 (RNE) in one dword (v_cvt_pk_bf16_f32)
static __device__ __forceinline__ unsigned pk2bf(float a, float b) {
    __hip_bfloat162 h = __float22bfloat162_rn(make_float2(a, b));
    unsigned r;
    __builtin_memcpy(&r, &h, sizeof(r));
    return r;
}

// Pack Wcat = [W1 | W3] (512 x 128) into bf16 B-fragment order (R1 mapping):
// bws[((kk*8+nt)*64 + l)*8 + j] = Wcat[kk*32 + 8*(l>>4) + j][nt*16 + (l&15)]
__global__ void prep_weights(const float* __restrict__ W1,
                             const float* __restrict__ W3,
                             short* __restrict__ bws) {
    int tid = blockIdx.x * blockDim.x + threadIdx.x;   // 0..65535
    int j  = tid & 7;
    int l  = (tid >> 3) & 63;
    int nt = (tid >> 9) & 7;
    int kk = tid >> 12;
    int k = kk * 32 + ((l >> 4) << 3) + j;
    int n = nt * 16 + (l & 15);
    float v = (n < 64) ? W1[k * 64 + n] : W3[k * 64 + (n - 64)];
    bws[tid] = f2bf(v);
}

// VERIFIED OPTIMUM (R10, 119.4 us): 8 waves, 16 rows/wave, 64 KiB half-K
// B-tile (re-staged mid-block), 2 blocks/CU, grid 2048. A-loads in 4-kk
// BURSTS (8 back-to-back dwordx4 = 512 B per row-visit) with the next
// burst issued under the current 32-MFMA block. Burst clumping was the
// single confirmed lever (+6%); depth/permute/NT/co-residency/linear-LDS
// all measured neutral or negative.
__global__ __launch_bounds__(512, 4)
void mf2_main(const float* __restrict__ probs, const float* __restrict__ x,
              const short* __restrict__ bws,
              const float* __restrict__ b1, const float* __restrict__ W2,
              const float* __restrict__ b2, const float* __restrict__ b3,
              const float* __restrict__ W4, const float* __restrict__ b4,
              float* __restrict__ out)
{
    __shared__ short bsh[256 * 128];   // 64 KiB: 8 kk-steps of packed [W1|W3]

    const int tid  = threadIdx.x;      // 0..511 (8 waves)
    const int lane = tid & 63;
    const int g    = lane >> 4;        // 0..3  (k-chunk group)
    const int m    = lane & 15;        // 0..15 (A-row / C-col)
    const long rowBase = (long)blockIdx.x * 128 + (tid >> 6) * 16;   // 16 rows/wave

    // A loads: lane reads 8 contiguous f32 of row (rowBase + m), k-chunk 8*g
    const float* xp = x + (rowBase + m) * 512 + g * 8;

    f32x4 ra[4][2];   // raw burst buffer (one 4-kk burst)
    s16x8 af[4];      // converted bf16 fragments for the burst being consumed

    // ---- burst 0 (kk 0..3): 8 back-to-back loads BEFORE staging ----
    #pragma unroll
    for (int p = 0; p < 4; ++p) {
        const float* pp = xp + p * 32;
        ra[p][0] = *(const f32x4*)pp;
        ra[p][1] = *(const f32x4*)(pp + 4);
    }

    // ---- stage K-half 0 (64 KiB) ----
    {
        const f32x4* src = (const f32x4*)bws;
        f32x4* dst = (f32x4*)bsh;
        #pragma unroll
        for (int it = 0; it < 8; ++it) {
            const int idx = it * 512 + tid;
            dst[idx] = src[idx];
        }
    }
    __syncthreads();

    const s16x8* bls = (const s16x8*)bsh + lane;

    f32x4 acc[8];
    #pragma unroll
    for (int nt = 0; nt < 8; ++nt)
        acc[nt] = (f32x4){0.f, 0.f, 0.f, 0.f};

    #pragma unroll
    for (int burst = 0; burst < 4; ++burst) {
        // convert current burst raw -> bf16 fragments (frees ra)
        #pragma unroll
        for (int s = 0; s < 4; ++s) {
            u32x4 pa;
            pa[0] = pk2bf(ra[s][0][0], ra[s][0][1]);
            pa[1] = pk2bf(ra[s][0][2], ra[s][0][3]);
            pa[2] = pk2bf(ra[s][1][0], ra[s][1][1]);
            pa[3] = pk2bf(ra[s][1][2], ra[s][1][3]);
            af[s] = __builtin_bit_cast(s16x8, pa);
        }

        // issue next burst (8 back-to-back loads, 512 B per row) — in flight
        // under the 32-MFMA block below
        if (burst < 3) {
            #pragma unroll
            for (int p = 0; p < 4; ++p) {
                const float* pp = xp + (burst + 1) * 128 + p * 32;
                ra[p][0] = *(const f32x4*)pp;
                ra[p][1] = *(const f32x4*)(pp + 4);
            }
        }

        // mid-block: re-stage B K-half 1 (burst-2 loads remain in flight)
        if (burst == 2) {
            __syncthreads();
            const f32x4* src = (const f32x4*)bws;
            f32x4* dst = (f32x4*)bsh;
            #pragma unroll
            for (int it = 0; it < 8; ++it) {
                const int idx = it * 512 + tid;
                dst[idx] = src[4096 + idx];
            }
            __syncthreads();
        }

        // 4 MFMA sub-steps for this burst; B fragments from LDS
        #pragma unroll
        for (int s = 0; s < 4; ++s) {
            const int k8 = (burst & 1) * 4 + s;   // kk within current B half
            #pragma unroll
            for (int nt = 0; nt < 8; ++nt) {
                s16x8 b = bls[k8 * 512 + nt * 64];
                acc[nt] = __builtin_amdgcn_mfma_f32_16x16x32_bf16(af[s], b, acc[nt], 0, 0, 0);
            }
        }
    }

    // ---- epilogue (weight/bias loads deferred past the loop) ----
    float w2r[4][4];
    float w4r[4][2];
    float biasr[8];
    #pragma unroll
    for (int nt = 0; nt < 4; ++nt) {
        const int col = m + 16 * nt;
        f32x4 w2v = *(const f32x4*)(W2 + col * 4);
        #pragma unroll
        for (int c = 0; c < 4; ++c) w2r[nt][c] = w2v[c];
        f32x2 w4v = *(const f32x2*)(W4 + col * 2);
        w4r[nt][0] = w4v[0]; w4r[nt][1] = w4v[1];
    }
    #pragma unroll
    for (int nt = 0; nt < 8; ++nt) {
        const int col = m + 16 * nt;
        biasr[nt] = (col < 64) ? b1[col] : b3[col - 64];
    }
    float b2v[4], b4v[2];
    #pragma unroll
    for (int c = 0; c < 4; ++c) b2v[c] = b2[c];
    #pragma unroll
    for (int c = 0; c < 2; ++c) b4v[c] = b4[c];

    // bias+relu, layer-2 partials, 16-lane butterfly reduce.
    // C layout: lane holds row 4*g + r, col m + 16*nt (reg r).
    float own[6] = {0.f, 0.f, 0.f, 0.f, 0.f, 0.f};
    #pragma unroll
    for (int r = 0; r < 4; ++r) {
        float v[6] = {0.f, 0.f, 0.f, 0.f, 0.f, 0.f};
        #pragma unroll
        for (int nt = 0; nt < 4; ++nt) {
            float h = fmaxf(acc[nt][r] + biasr[nt], 0.f);
            v[0] += h * w2r[nt][0];
            v[1] += h * w2r[nt][1];
            v[2] += h * w2r[nt][2];
            v[3] += h * w2r[nt][3];
        }
        #pragma unroll
        for (int j = 0; j < 4; ++j) {
            float h = fmaxf(acc[4 + j][r] + biasr[4 + j], 0.f);
            v[4] += h * w4r[j][0];
            v[5] += h * w4r[j][1];
        }
        #pragma unroll
        for (int msk = 1; msk <= 8; msk <<= 1) {
            #pragma unroll
            for (int c = 0; c < 6; ++c) v[c] += __shfl_xor(v[c], msk, 64);
        }
        if (m == r) {
            #pragma unroll
            for (int c = 0; c < 6; ++c) own[c] = v[c];
        }
    }

    // lanes m<4 finish one row each: sigmoid head + 2-class softmax
    if (m < 4) {
        const long row = rowBase + g * 4 + m;
        f32x4 pr = *(const f32x4*)(probs + row * 4);   // p00 p01 p10 p11
        float mu1[2], mu2[2], icv[2];
        #pragma unroll
        for (int c = 0; c < 2; ++c) {
            mu1[c] = 1.0f / (1.0f + __expf(-(own[c]     + b2v[c])));
            mu2[c] = 1.0f / (1.0f + __expf(-(own[2 + c] + b2v[2 + c])));
            icv[c] = 1.0f / (1.0f + __expf(-(own[4 + c] + b4v[c])));
        }
        float res[2];
        #pragma unroll
        for (int c = 0; c < 2; ++c) {
            float p0 = pr[c], p1 = pr[2 + c];
            float m12 = fminf(fmaxf(mu1[c], mu2[c]) + icv[c], 1.0f);
            res[c] = (p0 <= p1) ? (p0 * mu1[c] + (p1 - p0) * m12)
                                : (p1 * mu2[c] + (p0 - p1) * m12);
        }
        float d01 = res[0] - res[1];
        f32x2 o;
        o[0] = 1.0f / (1.0f + __expf(-d01));
        o[1] = 1.0f / (1.0f + __expf(d01));
        *(f32x2*)(out + row * 2) = o;
    }
}

extern "C" void kernel_launch(void* const* d_in, const int* in_sizes, int n_in,
                              void* d_out, int out_size, void* d_ws, size_t ws_size,
                              hipStream_t stream)
{
    const float* probs = (const float*)d_in[0];
    const float* x     = (const float*)d_in[1];
    const float* W1    = (const float*)d_in[2];
    const float* b1    = (const float*)d_in[3];
    const float* W2    = (const float*)d_in[4];
    const float* b2    = (const float*)d_in[5];
    const float* W3    = (const float*)d_in[6];
    const float* b3    = (const float*)d_in[7];
    const float* W4    = (const float*)d_in[8];
    const float* b4    = (const float*)d_in[9];
    float* out = (float*)d_out;
    short* bws = (short*)d_ws;   // 512*128 bf16 = 128 KiB

    hipLaunchKernelGGL(prep_weights, dim3(256), dim3(256), 0, stream, W1, W3, bws);
    hipLaunchKernelGGL(mf2_main, dim3(2048), dim3(512), 0, stream,
                       probs, x, bws, b1, W2, b2, b3, W4, b4, out);
}